// Round 12
// baseline (56.308 us; speedup 1.0000x reference)
//
#include <hip/hip_runtime.h>
#include <math.h>

#define B_ 2048
#define D_ 512
#define H_ 512
#define A_ 18
#define T_ 16
#define MTF 16
#define MAXTILESF 144

typedef __attribute__((ext_vector_type(8))) short short8;
typedef __attribute__((ext_vector_type(4))) float f32x4;

// ws layout:
//   [0..16384)      ints: [17..34) offsets[T+1] | [256..2304) order[B]  (fallback uses more)
//   PART_OFF 16K    float part[B][16][32]  (4 MB)
//   XSB_OFF  5M     bf16 xs_b[B][D]        (2 MB)
//   W2T_OFF  8M     bf16 w2t[T][32][512]   (512 KB, a>=18 zeroed)
#define PART_OFF 16384
#define XSB_OFF  (5 << 20)
#define W2T_OFF  (8 << 20)
#define WS_NEED  (12 << 20)

__device__ __forceinline__ unsigned short f2bf(float f) {
    union { float f; unsigned int u; } v; v.f = f;
    unsigned int u = v.u;
    return (unsigned short)((u + 0x7fffu + ((u >> 16) & 1u)) >> 16);
}

// ---- prep: [0,512) xs->bf16; [512,528) W2T; 528 sort ----
__global__ __launch_bounds__(256) void nk_prep(const float* __restrict__ xs,
                                               const float* __restrict__ W2,
                                               const int* __restrict__ task_id,
                                               unsigned short* __restrict__ xs_b,
                                               unsigned short* __restrict__ w2t,
                                               int* __restrict__ wsi) {
    int bid = blockIdx.x;
    int tid = threadIdx.x;
    if (bid < 512) {
        size_t off = ((size_t)bid * 256 + tid) * 8;
        float4 x0 = *(const float4*)(xs + off);
        float4 x1 = *(const float4*)(xs + off + 4);
        unsigned short uu[8] = { f2bf(x0.x), f2bf(x0.y), f2bf(x0.z), f2bf(x0.w),
                                 f2bf(x1.x), f2bf(x1.y), f2bf(x1.z), f2bf(x1.w) };
        *(uint4*)(xs_b + off) = *(const uint4*)uu;
    } else if (bid < 528) {
        // W2 [t][512][18] fp32 -> w2t [t][32][512] bf16 (a>=18 zero)
        int t = bid - 512;
        const float* src = W2 + (size_t)t * H_ * A_;
        unsigned short* dst = w2t + (size_t)t * 32 * H_;
#pragma unroll
        for (int i = 0; i < 2; ++i) {
            int h = tid * 2 + i;
            float v[A_];
#pragma unroll
            for (int a = 0; a < A_; ++a) v[a] = src[(size_t)h * A_ + a];
#pragma unroll
            for (int a = 0; a < A_; ++a) dst[(size_t)a * H_ + h] = f2bf(v[a]);
#pragma unroll
            for (int a = A_; a < 32; ++a) dst[(size_t)a * H_ + h] = 0;
        }
    } else {
        __shared__ int cnt[T_], cur[T_], soff[T_];
        if (tid < T_) { cnt[tid] = 0; cur[tid] = 0; }
        __syncthreads();
        for (int b = tid; b < B_; b += 256) atomicAdd(&cnt[task_id[b]], 1);
        __syncthreads();
        if (tid == 0) {
            int off = 0;
            for (int t = 0; t < T_; ++t) {
                soff[t] = off; wsi[17 + t] = off;
                off += cnt[t];
            }
            wsi[17 + T_] = off;
        }
        __syncthreads();
        for (int b = tid; b < B_; b += 256) {
            int t = task_id[b];
            int pos = atomicAdd(&cur[t], 1);
            wsi[256 + soff[t] + pos] = b;
        }
    }
}

// ---- gemm: block = (task, 32-col group), XCD-pinned, W1 B-frags in registers ----
// loops task rows in 16-row chunks: fc1 (16 MFMA) + relu + fc2 partial (1 MFMA)
__global__ __launch_bounds__(128) void nk_gemm(
        const unsigned short* __restrict__ xs_b,
        const float* __restrict__ W1,
        const unsigned short* __restrict__ w2t,
        const float* __restrict__ b1,
        float* __restrict__ part,
        const int* __restrict__ wsi) {
    __shared__ unsigned short h_lds[16][34];   // 1.1 KB bounce buffer

    int c = blockIdx.x;                 // XCD id (linear%8 == c)
    int s = blockIdx.y;                 // 0..31
    int t = c + (s >> 4) * 8;
    int cg = s & 15;                    // 32-col group of H

    int o = wsi[17 + t];
    int n = wsi[18 + t] - o;

    int tid = threadIdx.x, lane = tid & 63, w = tid >> 6;   // 2 waves
    int r15 = lane & 15, kg = lane >> 4;

    int c0 = cg * 32 + w * 16;          // wave's 16 fc1 cols

    // ---- load W1 B-fragments into registers (once): 16 ks-frags
    // lane r15 = col (c0+r15), kg*8+i = k offset within ks*32
    const float* wsrc = W1 + (size_t)t * D_ * H_ + c0 + r15;
    short8 breg[16];
#pragma unroll
    for (int ks = 0; ks < 16; ++ks) {
        float f[8];
#pragma unroll
        for (int i = 0; i < 8; ++i)
            f[i] = wsrc[(size_t)(ks * 32 + kg * 8 + i) * H_];
        unsigned short uu[8] = { f2bf(f[0]), f2bf(f[1]), f2bf(f[2]), f2bf(f[3]),
                                 f2bf(f[4]), f2bf(f[5]), f2bf(f[6]), f2bf(f[7]) };
        breg[ks] = *(const short8*)uu;
    }

    // ---- fc2 weight fragment (once): wave w -> a-tile w (a = w*16+r15), K=32
    const unsigned short* wa = w2t + ((size_t)t * 32 + w * 16 + r15) * H_
                               + cg * 32 + kg * 8;
    short8 w2frag = *(const short8*)wa;

    float bv = b1[t * H_ + c0 + r15];   // fc1 bias for this lane's C-col

    int nch = (n + 15) >> 4;
    for (int kr = 0; kr < nch; ++kr) {
        int rowbase = o + kr * 16;
        int rows = n - kr * 16; if (rows > 16) rows = 16;

        int ar = rowbase + (r15 < rows ? r15 : rows - 1);
        int arow = wsi[256 + ar];
        const unsigned short* ap = xs_b + (size_t)arow * D_ + kg * 8;

        f32x4 acc = {0.f, 0.f, 0.f, 0.f};
#pragma unroll
        for (int ks = 0; ks < 16; ++ks) {
            short8 af = *(const short8*)(ap + ks * 32);
            acc = __builtin_amdgcn_mfma_f32_16x16x32_bf16(af, breg[ks], acc, 0, 0, 0);
        }

        // bias + relu -> h_lds in C-layout (row = kg*4+j, col = w*16+r15)
#pragma unroll
        for (int j = 0; j < 4; ++j) {
            float v = acc[j] + bv;
            h_lds[kg * 4 + j][w * 16 + r15] = f2bf(v > 0.f ? v : 0.f);
        }
        __syncthreads();

        // fc2 partial over this block's 32 h-cols: A-frag from h_lds
        // (lane r15 = row, kg*8 = k offset; row stride 34*2B -> bank-clean)
        short8 hf = *(const short8*)&h_lds[r15][kg * 8];
        f32x4 p = {0.f, 0.f, 0.f, 0.f};
        p = __builtin_amdgcn_mfma_f32_16x16x32_bf16(hf, w2frag, p, 0, 0, 0);
#pragma unroll
        for (int j = 0; j < 4; ++j) {
            int lr = kg * 4 + j;
            if (lr < rows) {
                part[((size_t)(rowbase + lr) * 16 + cg) * 32 + w * 16 + r15] = p[j];
            }
        }
        __syncthreads();   // protect h_lds before next chunk
    }
}

// ---- final: sum 16 partials + bias, softmax, write outputs ----
__global__ __launch_bounds__(256) void nk_final(const float* __restrict__ part,
                                                const float* __restrict__ b2,
                                                const int* __restrict__ action,
                                                float* __restrict__ out,
                                                const int* __restrict__ wsi) {
    int r = blockIdx.x * 256 + threadIdx.x;
    if (r >= B_) return;
    int t = 0;
#pragma unroll
    for (int i = 1; i < T_; ++i) t += (r >= wsi[17 + i]) ? 1 : 0;
    int b = wsi[256 + r];

    float logits[A_];
#pragma unroll
    for (int a = 0; a < A_; ++a) logits[a] = b2[t * A_ + a];
    const float* pr = part + (size_t)r * 16 * 32;
#pragma unroll
    for (int cg = 0; cg < 16; ++cg) {
#pragma unroll
        for (int a = 0; a < A_; ++a) logits[a] += pr[cg * 32 + a];
    }
    float m = -1e30f;
#pragma unroll
    for (int a = 0; a < A_; ++a) m = fmaxf(m, logits[a]);
    float S = 0.f, sle = 0.f;
#pragma unroll
    for (int a = 0; a < A_; ++a) {
        float e = expf(logits[a] - m);
        S += e;
        sle += logits[a] * e;
    }
    float logZ = m + logf(S);
    int as = action[b];
    out[b] = (float)as;
    out[B_ + b] = logits[as] - logZ;
    out[2 * B_ + b] = logZ - sle / S;
}

// ---------------- fallback path (round-1, known-good) ----------------

__global__ void nk_init(int* wsi) { int i = threadIdx.x; if (i < 50) wsi[i] = 0; }

__global__ void nk_count(const int* task_id, int* wsi) {
    int b = blockIdx.x * blockDim.x + threadIdx.x;
    if (b < B_) atomicAdd(&wsi[1 + task_id[b]], 1);
}

__global__ void nk_plan(int* wsi) {
    int off = 0, tot = 0;
    for (int t = 0; t < T_; ++t) {
        wsi[17 + t] = off;
        int cnt = wsi[1 + t];
        int nt = (cnt + MTF - 1) / MTF;
        for (int k = 0; k < nt; ++k) wsi[50 + tot++] = (t << 16) | k;
        off += cnt;
    }
    wsi[17 + T_] = off;
    wsi[0] = tot;
}

__global__ void nk_scatter(const int* task_id, int* wsi) {
    int b = blockIdx.x * blockDim.x + threadIdx.x;
    if (b < B_) {
        int t = task_id[b];
        int pos = atomicAdd(&wsi[34 + t], 1);
        wsi[256 + wsi[17 + t] + pos] = b;
    }
}

__global__ __launch_bounds__(512) void nk_main(
        const float* __restrict__ xs, const float* __restrict__ W1,
        const float* __restrict__ b1, const float* __restrict__ W2,
        const float* __restrict__ b2, const int* __restrict__ task_id,
        const int* __restrict__ action, float* __restrict__ out,
        const int* __restrict__ wsi) {
    __shared__ float tile[MTF][D_];
    __shared__ int sidx[MTF];
    int bid = blockIdx.x;
    if (bid >= wsi[0]) return;
    int code = wsi[50 + bid];
    int t = code >> 16, kt = code & 0xffff;
    int off0 = wsi[17 + t], off1 = wsi[17 + t + 1];
    int base = off0 + kt * MTF;
    int rows = off1 - base; if (rows > MTF) rows = MTF;
    int tid = threadIdx.x;
    if (tid < MTF) sidx[tid] = (tid < rows) ? wsi[256 + base + tid] : -1;
    __syncthreads();
    for (int i = 0; i < MTF; ++i) {
        int b = sidx[i];
        tile[i][tid] = (b >= 0) ? xs[(size_t)b * D_ + tid] : 0.f;
    }
    __syncthreads();
    const float* w1p = W1 + (size_t)t * D_ * H_ + tid;
    float acc[MTF];
#pragma unroll
    for (int i = 0; i < MTF; ++i) acc[i] = 0.f;
    for (int d = 0; d < D_; d += 4) {
        float w0 = w1p[(size_t)(d + 0) * H_];
        float w1v = w1p[(size_t)(d + 1) * H_];
        float w2v = w1p[(size_t)(d + 2) * H_];
        float w3v = w1p[(size_t)(d + 3) * H_];
#pragma unroll
        for (int i = 0; i < MTF; ++i) {
            float4 x = *(const float4*)&tile[i][d];
            float a0 = fmaf(x.x, w0, acc[i]);
            a0 = fmaf(x.y, w1v, a0);
            a0 = fmaf(x.z, w2v, a0);
            acc[i] = fmaf(x.w, w3v, a0);
        }
    }
    __syncthreads();
    float b1v = b1[t * H_ + tid];
#pragma unroll
    for (int i = 0; i < MTF; ++i) {
        float h = acc[i] + b1v;
        tile[i][tid] = h > 0.f ? h : 0.f;
    }
    __syncthreads();
    int g = tid >> 5, l = tid & 31;
    float lg[A_];
#pragma unroll
    for (int a = 0; a < A_; ++a) lg[a] = 0.f;
    const float* w2base = W2 + (size_t)t * H_ * A_;
    for (int hh = l; hh < H_; hh += 32) {
        float hv = tile[g][hh];
        const float* wrow = w2base + (size_t)hh * A_;
#pragma unroll
        for (int a = 0; a < A_; ++a) lg[a] = fmaf(hv, wrow[a], lg[a]);
    }
#pragma unroll
    for (int a = 0; a < A_; ++a) {
        lg[a] += __shfl_down(lg[a], 16, 32);
        lg[a] += __shfl_down(lg[a], 8, 32);
        lg[a] += __shfl_down(lg[a], 4, 32);
        lg[a] += __shfl_down(lg[a], 2, 32);
        lg[a] += __shfl_down(lg[a], 1, 32);
    }
    if (l == 0 && g < rows) {
        int b = sidx[g];
        float logits[A_];
        float m = -1e30f;
#pragma unroll
        for (int a = 0; a < A_; ++a) {
            logits[a] = lg[a] + b2[t * A_ + a];
            m = fmaxf(m, logits[a]);
        }
        float S = 0.f, sle = 0.f;
#pragma unroll
        for (int a = 0; a < A_; ++a) {
            float e = expf(logits[a] - m);
            S += e;
            sle += logits[a] * e;
        }
        float logZ = m + logf(S);
        int as = action[b];
        out[b] = (float)as;
        out[B_ + b] = logits[as] - logZ;
        out[2 * B_ + b] = logZ - sle / S;
    }
}

extern "C" void kernel_launch(void* const* d_in, const int* in_sizes, int n_in,
                              void* d_out, int out_size, void* d_ws, size_t ws_size,
                              hipStream_t stream) {
    const float* xs = (const float*)d_in[0];
    const float* W1 = (const float*)d_in[1];
    const float* b1 = (const float*)d_in[2];
    const float* W2 = (const float*)d_in[3];
    const float* b2 = (const float*)d_in[4];
    const int* task_id = (const int*)d_in[5];
    const int* action = (const int*)d_in[6];
    float* out = (float*)d_out;

    if (ws_size >= WS_NEED) {
        unsigned char* wsb = (unsigned char*)d_ws;
        int* wsi = (int*)d_ws;
        float* part = (float*)(wsb + PART_OFF);
        unsigned short* xs_b = (unsigned short*)(wsb + XSB_OFF);
        unsigned short* w2t = (unsigned short*)(wsb + W2T_OFF);

        nk_prep<<<529, 256, 0, stream>>>(xs, W2, task_id, xs_b, w2t, wsi);
        nk_gemm<<<dim3(8, 32), 128, 0, stream>>>(xs_b, W1, w2t, b1, part, wsi);
        nk_final<<<(B_ + 255) / 256, 256, 0, stream>>>(part, b2, action, out, wsi);
    } else {
        int* wsi = (int*)d_ws;
        nk_init<<<1, 64, 0, stream>>>(wsi);
        nk_count<<<(B_ + 255) / 256, 256, 0, stream>>>(task_id, wsi);
        nk_plan<<<1, 1, 0, stream>>>(wsi);
        nk_scatter<<<(B_ + 255) / 256, 256, 0, stream>>>(task_id, wsi);
        nk_main<<<MAXTILESF, 512, 0, stream>>>(xs, W1, b1, W2, b2, task_id, action, out, wsi);
    }
}

// Round 13
// 31.925 us; speedup vs baseline: 1.7637x; 1.7637x over previous
//
#include <hip/hip_runtime.h>
#include <math.h>

#define B_ 2048
#define D_ 512
#define H_ 512
#define A_ 18
#define T_ 16
#define MTF 16
#define MAXTILESF 144
#define NSLOT 24

typedef __attribute__((ext_vector_type(8))) short short8;
typedef __attribute__((ext_vector_type(4))) float f32x4;

// ws layout:
//   [0..16384)    ints: [17..34) offsets[T+1] | [256..2304) order[B]  (fallback uses more)
//   W2F_OFF 3MB   bf16 w2f[T][2][16][64][8]   (512 KB, frag-order, a>=18 zeroed)
//   W1F_OFF 4MB   bf16 w1f[T][32][16][64][8]  (8 MB, frag-order)
#define W2F_OFF  (3 << 20)
#define W1F_OFF  (4 << 20)
#define WS_NEED  (12 << 20)

__device__ __forceinline__ unsigned short f2bf(float f) {
    union { float f; unsigned int u; } v; v.f = f;
    unsigned int u = v.u;
    return (unsigned short)((u + 0x7fffu + ((u >> 16) & 1u)) >> 16);
}

// ---- prep: [0,1024) W1 -> w1f frag-order bf16; [1024,1040) W2 -> w2f; 1040 sort ----
__global__ __launch_bounds__(256) void nk_prep(const float* __restrict__ W1,
                                               const float* __restrict__ W2,
                                               const int* __restrict__ task_id,
                                               unsigned short* __restrict__ w1f,
                                               unsigned short* __restrict__ w2f,
                                               int* __restrict__ wsi) {
    int bid = blockIdx.x;
    int tid = threadIdx.x;
    if (bid < 1024) {
        // block covers (t, k-range dy*64.., col-range hx*64..)
        __shared__ float tile[64][65];   // [k_local][col_local]
        int hx = bid & 7, dy = (bid >> 3) & 7, t = bid >> 6;
        const float* src = W1 + ((size_t)t * D_ + dy * 64) * H_ + hx * 64;
        int f4 = tid & 15, ry = tid >> 4;
#pragma unroll
        for (int i = 0; i < 4; ++i) {
            int row = ry + i * 16;
            float4 v = *(const float4*)(src + (size_t)row * H_ + f4 * 4);
            tile[row][f4 * 4 + 0] = v.x;
            tile[row][f4 * 4 + 1] = v.y;
            tile[row][f4 * 4 + 2] = v.z;
            tile[row][f4 * 4 + 3] = v.w;
        }
        __syncthreads();
        // frag-order store: chunk = (ntl 0..3, ksl 0..1, lane 0..63), 2 chunks/thread
        // w1f element addr = ((t*32 + hx*4+ntl)*16 + dy*2+ksl)*512 + lane*8
#pragma unroll
        for (int j = 0; j < 2; ++j) {
            int cch = tid * 2 + j;
            int ntl = cch >> 7;
            int ksl = (cch >> 6) & 1;
            int ln = cch & 63;
            int rr = ln & 15, kk = ln >> 4;
            unsigned short uu[8];
#pragma unroll
            for (int i = 0; i < 8; ++i)
                uu[i] = f2bf(tile[ksl * 32 + kk * 8 + i][ntl * 16 + rr]);
            size_t dst = (((size_t)t * 32 + hx * 4 + ntl) * 16 + dy * 2 + ksl) * 512
                         + (size_t)ln * 8;
            *(uint4*)(w1f + dst) = *(const uint4*)uu;
        }
    } else if (bid < 1040) {
        // W2 [t][512][18] fp32 -> w2f frag-order (a>=18 zero): 8 chunks/thread
        int t = bid - 1024;
        const float* src = W2 + (size_t)t * H_ * A_;
#pragma unroll
        for (int j = 0; j < 8; ++j) {
            int cch = tid * 8 + j;          // 0..2047
            int atl = cch >> 10;            // 0..1
            int ks = (cch >> 6) & 15;
            int ln = cch & 63;
            int rr = ln & 15, kk = ln >> 4;
            int a = atl * 16 + rr;
            unsigned short uu[8];
#pragma unroll
            for (int i = 0; i < 8; ++i) {
                int h = ks * 32 + kk * 8 + i;
                uu[i] = (a < A_) ? f2bf(src[(size_t)h * A_ + a]) : (unsigned short)0;
            }
            size_t dst = (((size_t)t * 2 + atl) * 16 + ks) * 512 + (size_t)ln * 8;
            *(uint4*)(w2f + dst) = *(const uint4*)uu;
        }
    } else {
        __shared__ int cnt[T_], cur[T_], soff[T_];
        if (tid < T_) { cnt[tid] = 0; cur[tid] = 0; }
        __syncthreads();
        for (int b = tid; b < B_; b += 256) atomicAdd(&cnt[task_id[b]], 1);
        __syncthreads();
        if (tid == 0) {
            int off = 0;
            for (int t = 0; t < T_; ++t) {
                soff[t] = off; wsi[17 + t] = off;
                off += cnt[t];
            }
            wsi[17 + T_] = off;
        }
        __syncthreads();
        for (int b = tid; b < B_; b += 256) {
            int t = task_id[b];
            int pos = atomicAdd(&cur[t], 1);
            wsi[256 + soff[t] + pos] = b;
        }
    }
}

// ---- fused, XCD-pinned: c = blockIdx.x handles tasks {c, c+8} ----
__global__ __launch_bounds__(512) void nk_fused(
        const float* __restrict__ xs,
        const unsigned short* __restrict__ w1f,
        const unsigned short* __restrict__ w2f,
        const float* __restrict__ b1, const float* __restrict__ b2,
        const int* __restrict__ action, float* __restrict__ out,
        const int* __restrict__ wsi) {
    __shared__ unsigned short x_lds[16][520];   // bf16 xs tile
    __shared__ unsigned short h_lds[16][520];   // bf16 h tile
    __shared__ float lg_lds[16][34];
    __shared__ int sidx[16];

    int c = blockIdx.x;                  // XCD id (linear%8 == blockIdx.x)
    int tid = threadIdx.x, lane = tid & 63, w = tid >> 6;
    int r15 = lane & 15, kg = lane >> 4;

    int o0 = wsi[17 + c],     n0 = wsi[18 + c] - o0;      // task c
    int o1 = wsi[17 + c + 8], n1 = wsi[18 + c + 8] - o1;  // task c+8
    int nt0 = (n0 + 15) >> 4, nt1 = (n1 + 15) >> 4;
    int ntot = nt0 + nt1;

    for (int u = blockIdx.y; u < ntot; u += NSLOT) {
        int t, kt, off0, rT;
        if (u < nt0) { t = c; kt = u; off0 = o0; rT = n0; }
        else { t = c + 8; kt = u - nt0; off0 = o1; rT = n1; }
        int rowbase = off0 + kt * 16;
        int rows = rT - kt * 16; if (rows > 16) rows = 16;

        if (tid < 16) sidx[tid] = wsi[256 + rowbase + (tid < rows ? tid : rows - 1)];
        __syncthreads();

        // stage 16 xs rows fp32 -> bf16 LDS (thread: row=tid>>5, 16 cols)
        {
            int row = tid >> 5, col = (tid & 31) * 16;
            const float* src = xs + (size_t)sidx[row] * D_ + col;
            float4 v0 = *(const float4*)(src);
            float4 v1 = *(const float4*)(src + 4);
            float4 v2 = *(const float4*)(src + 8);
            float4 v3 = *(const float4*)(src + 12);
            unsigned short uu[16] = {
                f2bf(v0.x), f2bf(v0.y), f2bf(v0.z), f2bf(v0.w),
                f2bf(v1.x), f2bf(v1.y), f2bf(v1.z), f2bf(v1.w),
                f2bf(v2.x), f2bf(v2.y), f2bf(v2.z), f2bf(v2.w),
                f2bf(v3.x), f2bf(v3.y), f2bf(v3.z), f2bf(v3.w) };
            *(uint4*)&x_lds[row][col]     = *(const uint4*)&uu[0];
            *(uint4*)&x_lds[row][col + 8] = *(const uint4*)&uu[8];
        }
        __syncthreads();

        // ---- fc1: wave w covers n-tiles w*4..w*4+3 (cols w*64..w*64+63)
        // B-loads are frag-order: lane*16B contiguous -> one 1KB transaction/load
        const unsigned short* bw = w1f + ((size_t)t * 32 + w * 4) * 16 * 512
                                   + (size_t)lane * 8;
        f32x4 acc0 = {0.f,0.f,0.f,0.f}, acc1 = {0.f,0.f,0.f,0.f};
        f32x4 acc2 = {0.f,0.f,0.f,0.f}, acc3 = {0.f,0.f,0.f,0.f};
#pragma unroll
        for (int ks = 0; ks < 16; ++ks) {
            short8 af = *(const short8*)&x_lds[r15][ks * 32 + kg * 8];
            short8 b0 = *(const short8*)(bw + (size_t)(0 * 16 + ks) * 512);
            short8 b1f = *(const short8*)(bw + (size_t)(1 * 16 + ks) * 512);
            short8 b2f = *(const short8*)(bw + (size_t)(2 * 16 + ks) * 512);
            short8 b3f = *(const short8*)(bw + (size_t)(3 * 16 + ks) * 512);
            acc0 = __builtin_amdgcn_mfma_f32_16x16x32_bf16(af, b0, acc0, 0, 0, 0);
            acc1 = __builtin_amdgcn_mfma_f32_16x16x32_bf16(af, b1f, acc1, 0, 0, 0);
            acc2 = __builtin_amdgcn_mfma_f32_16x16x32_bf16(af, b2f, acc2, 0, 0, 0);
            acc3 = __builtin_amdgcn_mfma_f32_16x16x32_bf16(af, b3f, acc3, 0, 0, 0);
        }

        int colb = w * 64 + r15;
        float bv0 = b1[t * H_ + colb];
        float bv1 = b1[t * H_ + colb + 16];
        float bv2 = b1[t * H_ + colb + 32];
        float bv3 = b1[t * H_ + colb + 48];
#pragma unroll
        for (int j = 0; j < 4; ++j) {
            int row = kg * 4 + j;
            float v;
            v = acc0[j] + bv0; h_lds[row][colb]      = f2bf(v > 0.f ? v : 0.f);
            v = acc1[j] + bv1; h_lds[row][colb + 16] = f2bf(v > 0.f ? v : 0.f);
            v = acc2[j] + bv2; h_lds[row][colb + 32] = f2bf(v > 0.f ? v : 0.f);
            v = acc3[j] + bv3; h_lds[row][colb + 48] = f2bf(v > 0.f ? v : 0.f);
        }
        __syncthreads();

        // ---- fc2: waves 0,1; wave w = a-tile w (a-cols w*16..+15), K=512
        if (w < 2) {
            const unsigned short* wa = w2f + ((size_t)t * 2 + w) * 16 * 512
                                       + (size_t)lane * 8;
            f32x4 c0 = {0.f,0.f,0.f,0.f};
#pragma unroll
            for (int ks = 0; ks < 16; ++ks) {
                short8 hf = *(const short8*)&h_lds[r15][ks * 32 + kg * 8];
                short8 w0 = *(const short8*)(wa + (size_t)ks * 512);
                c0 = __builtin_amdgcn_mfma_f32_16x16x32_bf16(hf, w0, c0, 0, 0, 0);
            }
            int a = w * 16 + r15;
            float bb = (a < A_) ? b2[t * A_ + a] : 0.f;
#pragma unroll
            for (int j = 0; j < 4; ++j) {
                lg_lds[kg * 4 + j][a] = c0[j] + bb;
            }
        }
        __syncthreads();

        // ---- softmax + outputs: one thread per row
        if (tid < rows) {
            int b = sidx[tid];
            float logits[A_];
            float m = -1e30f;
#pragma unroll
            for (int a = 0; a < A_; ++a) {
                logits[a] = lg_lds[tid][a];
                m = fmaxf(m, logits[a]);
            }
            float S = 0.f, sle = 0.f;
#pragma unroll
            for (int a = 0; a < A_; ++a) {
                float e = expf(logits[a] - m);
                S += e;
                sle += logits[a] * e;
            }
            float logZ = m + logf(S);
            int as = action[b];
            out[b] = (float)as;
            out[B_ + b] = logits[as] - logZ;
            out[2 * B_ + b] = logZ - sle / S;
        }
        __syncthreads();   // protect sidx/x_lds/lg_lds before next unit
    }
}

// ---------------- fallback path (round-1, known-good) ----------------

__global__ void nk_init(int* wsi) { int i = threadIdx.x; if (i < 50) wsi[i] = 0; }

__global__ void nk_count(const int* task_id, int* wsi) {
    int b = blockIdx.x * blockDim.x + threadIdx.x;
    if (b < B_) atomicAdd(&wsi[1 + task_id[b]], 1);
}

__global__ void nk_plan(int* wsi) {
    int off = 0, tot = 0;
    for (int t = 0; t < T_; ++t) {
        wsi[17 + t] = off;
        int cnt = wsi[1 + t];
        int nt = (cnt + MTF - 1) / MTF;
        for (int k = 0; k < nt; ++k) wsi[50 + tot++] = (t << 16) | k;
        off += cnt;
    }
    wsi[17 + T_] = off;
    wsi[0] = tot;
}

__global__ void nk_scatter(const int* task_id, int* wsi) {
    int b = blockIdx.x * blockDim.x + threadIdx.x;
    if (b < B_) {
        int t = task_id[b];
        int pos = atomicAdd(&wsi[34 + t], 1);
        wsi[256 + wsi[17 + t] + pos] = b;
    }
}

__global__ __launch_bounds__(512) void nk_main(
        const float* __restrict__ xs, const float* __restrict__ W1,
        const float* __restrict__ b1, const float* __restrict__ W2,
        const float* __restrict__ b2, const int* __restrict__ task_id,
        const int* __restrict__ action, float* __restrict__ out,
        const int* __restrict__ wsi) {
    __shared__ float tile[MTF][D_];
    __shared__ int sidx[MTF];
    int bid = blockIdx.x;
    if (bid >= wsi[0]) return;
    int code = wsi[50 + bid];
    int t = code >> 16, kt = code & 0xffff;
    int off0 = wsi[17 + t], off1 = wsi[17 + t + 1];
    int base = off0 + kt * MTF;
    int rows = off1 - base; if (rows > MTF) rows = MTF;
    int tid = threadIdx.x;
    if (tid < MTF) sidx[tid] = (tid < rows) ? wsi[256 + base + tid] : -1;
    __syncthreads();
    for (int i = 0; i < MTF; ++i) {
        int b = sidx[i];
        tile[i][tid] = (b >= 0) ? xs[(size_t)b * D_ + tid] : 0.f;
    }
    __syncthreads();
    const float* w1p = W1 + (size_t)t * D_ * H_ + tid;
    float acc[MTF];
#pragma unroll
    for (int i = 0; i < MTF; ++i) acc[i] = 0.f;
    for (int d = 0; d < D_; d += 4) {
        float w0 = w1p[(size_t)(d + 0) * H_];
        float w1v = w1p[(size_t)(d + 1) * H_];
        float w2v = w1p[(size_t)(d + 2) * H_];
        float w3v = w1p[(size_t)(d + 3) * H_];
#pragma unroll
        for (int i = 0; i < MTF; ++i) {
            float4 x = *(const float4*)&tile[i][d];
            float a0 = fmaf(x.x, w0, acc[i]);
            a0 = fmaf(x.y, w1v, a0);
            a0 = fmaf(x.z, w2v, a0);
            acc[i] = fmaf(x.w, w3v, a0);
        }
    }
    __syncthreads();
    float b1v = b1[t * H_ + tid];
#pragma unroll
    for (int i = 0; i < MTF; ++i) {
        float h = acc[i] + b1v;
        tile[i][tid] = h > 0.f ? h : 0.f;
    }
    __syncthreads();
    int g = tid >> 5, l = tid & 31;
    float lg[A_];
#pragma unroll
    for (int a = 0; a < A_; ++a) lg[a] = 0.f;
    const float* w2base = W2 + (size_t)t * H_ * A_;
    for (int hh = l; hh < H_; hh += 32) {
        float hv = tile[g][hh];
        const float* wrow = w2base + (size_t)hh * A_;
#pragma unroll
        for (int a = 0; a < A_; ++a) lg[a] = fmaf(hv, wrow[a], lg[a]);
    }
#pragma unroll
    for (int a = 0; a < A_; ++a) {
        lg[a] += __shfl_down(lg[a], 16, 32);
        lg[a] += __shfl_down(lg[a], 8, 32);
        lg[a] += __shfl_down(lg[a], 4, 32);
        lg[a] += __shfl_down(lg[a], 2, 32);
        lg[a] += __shfl_down(lg[a], 1, 32);
    }
    if (l == 0 && g < rows) {
        int b = sidx[g];
        float logits[A_];
        float m = -1e30f;
#pragma unroll
        for (int a = 0; a < A_; ++a) {
            logits[a] = lg[a] + b2[t * A_ + a];
            m = fmaxf(m, logits[a]);
        }
        float S = 0.f, sle = 0.f;
#pragma unroll
        for (int a = 0; a < A_; ++a) {
            float e = expf(logits[a] - m);
            S += e;
            sle += logits[a] * e;
        }
        float logZ = m + logf(S);
        int as = action[b];
        out[b] = (float)as;
        out[B_ + b] = logits[as] - logZ;
        out[2 * B_ + b] = logZ - sle / S;
    }
}

extern "C" void kernel_launch(void* const* d_in, const int* in_sizes, int n_in,
                              void* d_out, int out_size, void* d_ws, size_t ws_size,
                              hipStream_t stream) {
    const float* xs = (const float*)d_in[0];
    const float* W1 = (const float*)d_in[1];
    const float* b1 = (const float*)d_in[2];
    const float* W2 = (const float*)d_in[3];
    const float* b2 = (const float*)d_in[4];
    const int* task_id = (const int*)d_in[5];
    const int* action = (const int*)d_in[6];
    float* out = (float*)d_out;

    if (ws_size >= WS_NEED) {
        unsigned char* wsb = (unsigned char*)d_ws;
        int* wsi = (int*)d_ws;
        unsigned short* w2f = (unsigned short*)(wsb + W2F_OFF);
        unsigned short* w1f = (unsigned short*)(wsb + W1F_OFF);

        nk_prep<<<1041, 256, 0, stream>>>(W1, W2, task_id, w1f, w2f, wsi);
        nk_fused<<<dim3(8, NSLOT), 512, 0, stream>>>(xs, w1f, w2f, b1, b2,
                                                     action, out, wsi);
    } else {
        int* wsi = (int*)d_ws;
        nk_init<<<1, 64, 0, stream>>>(wsi);
        nk_count<<<(B_ + 255) / 256, 256, 0, stream>>>(task_id, wsi);
        nk_plan<<<1, 1, 0, stream>>>(wsi);
        nk_scatter<<<(B_ + 255) / 256, 256, 0, stream>>>(task_id, wsi);
        nk_main<<<MAXTILESF, 512, 0, stream>>>(xs, W1, b1, W2, b2, task_id, action, out, wsi);
    }
}